// Round 14
// baseline (207.842 us; speedup 1.0000x reference)
//
#include <hip/hip_runtime.h>

// TeamMovementModel R14: 16-wave split-gate LSTM, 4 waves/SIMD under the
// register wall. R13 showed the step is stall-bound (VALU cut -> no wall
// change); R8..R13's 216 regs/wave capped us at 2 lockstep waves/SIMD.
// Here: per-wave M=32 (2 m-tiles, afr=40 AGPR, ~110 regs/wave) -> 1024-thr
// blocks at waves_per_eu(4,4) = 4 waves/SIMD.
//   wave w (0..7)  "heavy": gates i,g of row-group w; cell update; h->B.
//   wave w+8       "light": gates f,o (activated sigma) -> LDS exchange.
// Pairwise sync: light writes flags[w]=s+1 after its gate writes (monotonic,
// race-free: light can't overrun - the per-step __syncthreads for B gates it).
// Heavy spins on the flag (broadcast LDS read), reads sigma(f),sigma(o),
// finishes c,h. Light's path is shorter -> staggered barrier arrivals ->
// 4 distinct instruction streams per SIMD fill each other's stalls.

#define HDIM 128
#define TSTEPS 128
#define NPLAYER 1408
#define NSEQ 1472
#define NB 8
#define NBLK (NSEQ / NB)        // 184
#define NPBLK (NPLAYER / NB)    // 176
#define KT 5                    // k-tiles of 32 (K_aug = 160)
#define BSTR 168                // fp16 per B row (336 B stride)
#define XSTR 258                // floats per x col
#define HSTR 132                // floats per hbuf row
#define ESTR 10                 // floats per exchange row (bank-spread)

typedef _Float16 f16x8 __attribute__((ext_vector_type(8)));
typedef _Float16 f16x2 __attribute__((ext_vector_type(2)));
typedef float    f32x4 __attribute__((ext_vector_type(4)));
typedef float    f32x2 __attribute__((ext_vector_type(2)));

#define LOG2E 1.44269504f

__device__ __forceinline__ f32x2 exp2v(f32x2 a) {
    return (f32x2){__builtin_amdgcn_exp2f(a[0]), __builtin_amdgcn_exp2f(a[1])};
}
__device__ __forceinline__ f32x2 rcpv(f32x2 a) {
    return (f32x2){__builtin_amdgcn_rcpf(a[0]), __builtin_amdgcn_rcpf(a[1])};
}
// select+swap in one DPP: lanes nn<8 keep `keep`; lanes nn>=8 get lane^8's `src`.
__device__ __forceinline__ float dpp_sel8(float keep, float src) {
    return __int_as_float(__builtin_amdgcn_update_dpp(
        __float_as_int(keep), __float_as_int(src), 0x128 /*ror:8*/, 0xF, 0xC, false));
}

__global__ void __launch_bounds__(1024)
__attribute__((amdgpu_waves_per_eu(4, 4)))
lstm_fc_kernel(const float* __restrict__ x_players, const float* __restrict__ x_ball,
               const float* __restrict__ p_w_ih, const float* __restrict__ p_w_hh,
               const float* __restrict__ p_b_ih, const float* __restrict__ p_b_hh,
               const float* __restrict__ b_w_ih, const float* __restrict__ b_w_hh,
               const float* __restrict__ b_b_ih, const float* __restrict__ b_b_hh,
               const float* __restrict__ fc_w, const float* __restrict__ fc_b,
               float* __restrict__ out)
{
    const int tid  = threadIdx.x;
    const int blk  = blockIdx.x;          // 0..183; 176..183 ball
    const int w    = tid >> 6;            // wave 0..15
    const int lane = tid & 63;
    const int nn   = lane & 15;
    const int q    = lane >> 4;
    const int b3   = (nn >> 3) & 1;
    const int w8   = w & 7;               // row-group
    const bool heavy = (w < 8);           // i,g + cell update

    const bool ball = (blk >= NPBLK);
    const float* w_ih = ball ? b_w_ih : p_w_ih;
    const float* w_hh = ball ? b_w_hh : p_w_hh;
    const float* bih  = ball ? b_b_ih : p_b_ih;
    const float* bhh  = ball ? b_b_hh : p_b_hh;
    const float* xg   = ball ? (x_ball    + (size_t)(blk - NPBLK) * NB * TSTEPS * 2)
                             : (x_players + (size_t)blk * NB * TSTEPS * 2);

    __shared__ __align__(16) _Float16 b_sh[2][NB * BSTR];
    __shared__ __align__(16) float x_sh[NB * XSTR];
    __shared__ float exF[HDIM * ESTR];    // sigma(f) [row][col]
    __shared__ float exO[HDIM * ESTR];    // sigma(o)
    __shared__ int   flags[8];            // per-rowgroup step counter
    __shared__ __align__(16) float hbuf[NB * HSTR];
    __shared__ float vout[NB * 40];

    for (int i = tid; i < NB * 256; i += 1024)
        x_sh[(i >> 8) * XSTR + (i & 255)] = xg[i];
    for (int i = tid; i < 2 * NB * BSTR / 2; i += 1024)
        ((int*)b_sh)[i] = 0;
    if (tid < 8) flags[tid] = 0;

    // ---- A fragments: 2 m-tiles/wave. t1 = w (gate i|f), t2 = w+16 (g|o).
    // tile t covers gate-rows [16t, 16t+16); a[j] = A[m=nn][k=32kt+8q+j]
    f16x8 afr[2][KT];
    #pragma unroll
    for (int ti = 0; ti < 2; ++ti) {
        const int r = 16 * (w + 16 * ti) + nn;
        const float* wr = w_hh + (size_t)r * HDIM;
        #pragma unroll
        for (int kt = 0; kt < 4; ++kt) {
            const float* p = wr + kt * 32 + q * 8;
            f16x8 a8;
            #pragma unroll
            for (int j = 0; j < 8; ++j) a8[j] = (_Float16)p[j];
            afr[ti][kt] = a8;
        }
        f16x8 a8 = {};
        if (q == 0) {
            a8[0] = (_Float16)w_ih[2 * r];
            a8[1] = (_Float16)w_ih[2 * r + 1];
            a8[2] = (_Float16)(bih[r] + bhh[r]);
        }
        afr[ti][4] = a8;
    }

    const int cc = nn & 7;                       // owned seq col
    const int r0 = 16 * w8 + 4 * q + 2 * b3;     // first of 2 owned h-rows
    f32x2 c = (f32x2){0.f, 0.f};
    f32x2 h = (f32x2){0.f, 0.f};

    f32x4 zero4 = (f32x4){0.f, 0.f, 0.f, 0.f};
    asm volatile("" : "+v"(zero4));

    __syncthreads();
    if (tid >= 512 && tid < 512 + NB) {   // wave 8 (light): x(0) + '1' aug
        const int j = tid - 512;
        _Float16* br0 = &b_sh[0][j * BSTR];
        br0[128] = (_Float16)x_sh[j * XSTR];
        br0[129] = (_Float16)x_sh[j * XSTR + 1];
        br0[130] = (_Float16)1.0f;
        b_sh[1][j * BSTR + 130] = (_Float16)1.0f;
    }
    __syncthreads();

    f16x8 bfr[KT] = {};   // lanes nn>=8 keep constant-zero B frags

    #pragma unroll 1
    for (int s = 0; s < TSTEPS; ++s) {
        const bool last = (s == TSTEPS - 1);
        const _Float16* bc = &b_sh[s & 1][0];
        _Float16*       bn = &b_sh[(s & 1) ^ 1][0];

        if (nn < 8) {
            #pragma unroll
            for (int kt = 0; kt < KT; ++kt)
                bfr[kt] = *(const f16x8*)(bc + nn * BSTR + kt * 32 + q * 8);
        }

        f32x4 acc[2];
        #pragma unroll
        for (int ti = 0; ti < 2; ++ti)
            acc[ti] = __builtin_amdgcn_mfma_f32_16x16x32_f16(afr[ti][4], bfr[4], zero4, 0, 0, 0);
        #pragma unroll
        for (int kt = 0; kt < 4; ++kt)
            #pragma unroll
            for (int ti = 0; ti < 2; ++ti)
                acc[ti] = __builtin_amdgcn_mfma_f32_16x16x32_f16(afr[ti][kt], bfr[kt], acc[ti], 0, 0, 0);

        // x(s+1) into next buffer (light wave 8 lanes; independent)
        if (!last && tid >= 512 && tid < 512 + NB) {
            const int j = tid - 512;
            const float x0 = x_sh[j * XSTR + 2 * (s + 1)];
            const float x1 = x_sh[j * XSTR + 2 * (s + 1) + 1];
            *(f16x2*)&bn[j * BSTR + 128] = (f16x2){(_Float16)x0, (_Float16)x1};
        }

        // sel8: u[ti] = rows r0, r0+1 of tile ti, col cc
        f32x2 u0, u1;
        u0[0] = dpp_sel8(acc[0][0], acc[0][2]);
        u0[1] = dpp_sel8(acc[0][1], acc[0][3]);
        u1[0] = dpp_sel8(acc[1][0], acc[1][2]);
        u1[1] = dpp_sel8(acc[1][1], acc[1][3]);

        if (!heavy) {
            // light: sigma(f), sigma(o) -> exchange, then flag
            const f32x2 ef = exp2v(u0 * -LOG2E);
            const f32x2 eo = exp2v(u1 * -LOG2E);
            const f32x2 ff = rcpv(ef + 1.0f);
            const f32x2 oo = rcpv(eo + 1.0f);
            exF[r0 * ESTR + cc]       = ff[0];
            exF[(r0 + 1) * ESTR + cc] = ff[1];
            exO[r0 * ESTR + cc]       = oo[0];
            exO[(r0 + 1) * ESTR + cc] = oo[1];
            __threadfence_block();
            if (lane == 0) ((volatile int*)flags)[w8] = s + 1;
        } else {
            // heavy: i*g via merged rcp, spin for partner's f,o, cell update
            const f32x2 ei = exp2v(u0 * -LOG2E);
            const f32x2 eg = exp2v(u1 * (2.0f * LOG2E));
            const f32x2 ig = (eg - 1.0f) * rcpv((ei + 1.0f) * (eg + 1.0f));
            while (((volatile int*)flags)[w8] <= s) { }
            __threadfence_block();
            const f32x2 ff = (f32x2){exF[r0 * ESTR + cc], exF[(r0 + 1) * ESTR + cc]};
            const f32x2 oo = (f32x2){exO[r0 * ESTR + cc], exO[(r0 + 1) * ESTR + cc]};
            c = __builtin_elementwise_fma(ff, c, ig);
            c = __builtin_elementwise_min(__builtin_elementwise_max(c, (f32x2){-15.f, -15.f}),
                                          (f32x2){15.f, 15.f});
            const f32x2 ec = exp2v(c * (2.0f * LOG2E));
            h = oo * (ec - 1.0f) * rcpv(ec + 1.0f);
            if (!last)
                *(f16x2*)&bn[cc * BSTR + r0] = (f16x2){(_Float16)h[0], (_Float16)h[1]};
        }

        if (!last) __syncthreads();

        // loop-carried AGPR pins: block rematerialization (R1..R5 failure mode)
        asm volatile("" : "+a"(afr[0][0]), "+a"(afr[0][1]), "+a"(afr[0][2]), "+a"(afr[0][3]), "+a"(afr[0][4]));
        asm volatile("" : "+a"(afr[1][0]), "+a"(afr[1][1]), "+a"(afr[1][2]), "+a"(afr[1][3]), "+a"(afr[1][4]));
        asm volatile("" : "+v"(zero4));
    }

    // ---- final h -> LDS (fp32), then fused FC epilogue ----
    if (heavy) {
        hbuf[cc * HSTR + r0]     = h[0];
        hbuf[cc * HSTR + r0 + 1] = h[1];
    }
    __syncthreads();

    if (!ball) {
        for (int o = tid; o < NB * 40; o += 1024) {
            const int j = o / 40, row = o - j * 40;
            const float* wr = fc_w + (size_t)row * 2 * HDIM;        // cols 0..127
            const float* hp = &hbuf[j * HSTR];
            float a0 = fc_b[row], a1 = 0.f, a2 = 0.f, a3 = 0.f;
            #pragma unroll
            for (int k = 0; k < HDIM; k += 4) {
                float4 wv = *(const float4*)(wr + k);
                float4 hv = *(const float4*)(hp + k);
                a0 = __builtin_fmaf(wv.x, hv.x, a0);
                a1 = __builtin_fmaf(wv.y, hv.y, a1);
                a2 = __builtin_fmaf(wv.z, hv.z, a2);
                a3 = __builtin_fmaf(wv.w, hv.w, a3);
            }
            atomicAdd(&out[(size_t)(NB * blk + j) * 40 + row], (a0 + a1) + (a2 + a3));
        }
    } else {
        for (int o = tid; o < NB * 40; o += 1024) {
            const int cb = o / 40, row = o - cb * 40;
            const float* wr = fc_w + (size_t)row * 2 * HDIM + HDIM;  // cols 128..255
            const float* hp = &hbuf[cb * HSTR];
            float a0 = 0.f, a1 = 0.f, a2 = 0.f, a3 = 0.f;
            #pragma unroll
            for (int k = 0; k < HDIM; k += 4) {
                float4 wv = *(const float4*)(wr + k);
                float4 hv = *(const float4*)(hp + k);
                a0 = __builtin_fmaf(wv.x, hv.x, a0);
                a1 = __builtin_fmaf(wv.y, hv.y, a1);
                a2 = __builtin_fmaf(wv.z, hv.z, a2);
                a3 = __builtin_fmaf(wv.w, hv.w, a3);
            }
            vout[cb * 40 + row] = (a0 + a1) + (a2 + a3);
        }
        __syncthreads();
        const int base_batch = (blk - NPBLK) * NB;
        for (int o = tid; o < NB * 22 * 40; o += 1024) {
            const int cb = o / 880, rem = o - cb * 880;
            const int p = rem / 40, row = rem - p * 40;
            atomicAdd(&out[(size_t)((base_batch + cb) * 22 + p) * 40 + row],
                      vout[cb * 40 + row]);
        }
    }
}

extern "C" void kernel_launch(void* const* d_in, const int* in_sizes, int n_in,
                              void* d_out, int out_size, void* d_ws, size_t ws_size,
                              hipStream_t stream) {
    const float* x_players = (const float*)d_in[0];
    const float* x_ball    = (const float*)d_in[1];
    const float* p_w_ih    = (const float*)d_in[2];
    const float* p_w_hh    = (const float*)d_in[3];
    const float* p_b_ih    = (const float*)d_in[4];
    const float* p_b_hh    = (const float*)d_in[5];
    const float* b_w_ih    = (const float*)d_in[6];
    const float* b_w_hh    = (const float*)d_in[7];
    const float* b_b_ih    = (const float*)d_in[8];
    const float* b_b_hh    = (const float*)d_in[9];
    const float* fc_w      = (const float*)d_in[10];
    const float* fc_b      = (const float*)d_in[11];

    hipMemsetAsync(d_out, 0, (size_t)out_size * sizeof(float), stream);

    lstm_fc_kernel<<<dim3(NBLK), dim3(1024), 0, stream>>>(
        x_players, x_ball, p_w_ih, p_w_hh, p_b_ih, p_b_hh,
        b_w_ih, b_w_hh, b_b_ih, b_b_hh, fc_w, fc_b, (float*)d_out);
}

// Round 15
// 205.224 us; speedup vs baseline: 1.0128x; 1.0128x over previous
//
#include <hip/hip_runtime.h>

// TeamMovementModel R15: R14's 4-wave/SIMD split-gate structure with the
// exchange FIXED. R14 regressed (144.9us) purely on LDS conflicts (1.9e6 ->
// 6.8e6): its exF/exO were indexed [row][col] with stride 10 -> up to 8-way
// bank collisions on the recurrence critical path. Fix: producer lane (light,
// group w8, lane L) and consumer lane (heavy, w8, L) share the same (r0,cc),
// so the exchange is flat lane-indexed: exFO[w8*64+lane] as ONE f32x4 =
// one conflict-free ds_write_b128 / ds_read_b128 pair.
//   wave w (0..7)  "heavy": gates i,g of row-group w; cell update; h->B.
//   wave w+8       "light": gates f,o (activated) -> packed exchange + flag.
// 16 waves x M=32 rows (2 m-tiles, afr=40 AGPR, ~100 regs/wave) -> 4 waves/
// SIMD at waves_per_eu(4,4): 4 distinct instruction streams fill stalls.

#define HDIM 128
#define TSTEPS 128
#define NPLAYER 1408
#define NSEQ 1472
#define NB 8
#define NBLK (NSEQ / NB)        // 184
#define NPBLK (NPLAYER / NB)    // 176
#define KT 5                    // k-tiles of 32 (K_aug = 160)
#define BSTR 168                // fp16 per B row (336 B stride)
#define XSTR 258                // floats per x col
#define HSTR 132                // floats per hbuf row

typedef _Float16 f16x8 __attribute__((ext_vector_type(8)));
typedef _Float16 f16x2 __attribute__((ext_vector_type(2)));
typedef float    f32x4 __attribute__((ext_vector_type(4)));
typedef float    f32x2 __attribute__((ext_vector_type(2)));

#define LOG2E 1.44269504f

__device__ __forceinline__ f32x2 exp2v(f32x2 a) {
    return (f32x2){__builtin_amdgcn_exp2f(a[0]), __builtin_amdgcn_exp2f(a[1])};
}
__device__ __forceinline__ f32x2 rcpv(f32x2 a) {
    return (f32x2){__builtin_amdgcn_rcpf(a[0]), __builtin_amdgcn_rcpf(a[1])};
}
// select+swap in one DPP: lanes nn<8 keep `keep`; lanes nn>=8 get lane^8's `src`.
__device__ __forceinline__ float dpp_sel8(float keep, float src) {
    return __int_as_float(__builtin_amdgcn_update_dpp(
        __float_as_int(keep), __float_as_int(src), 0x128 /*ror:8*/, 0xF, 0xC, false));
}

__global__ void __launch_bounds__(1024)
__attribute__((amdgpu_waves_per_eu(4, 4)))
lstm_fc_kernel(const float* __restrict__ x_players, const float* __restrict__ x_ball,
               const float* __restrict__ p_w_ih, const float* __restrict__ p_w_hh,
               const float* __restrict__ p_b_ih, const float* __restrict__ p_b_hh,
               const float* __restrict__ b_w_ih, const float* __restrict__ b_w_hh,
               const float* __restrict__ b_b_ih, const float* __restrict__ b_b_hh,
               const float* __restrict__ fc_w, const float* __restrict__ fc_b,
               float* __restrict__ out)
{
    const int tid  = threadIdx.x;
    const int blk  = blockIdx.x;          // 0..183; 176..183 ball
    const int w    = tid >> 6;            // wave 0..15
    const int lane = tid & 63;
    const int nn   = lane & 15;
    const int q    = lane >> 4;
    const int b3   = (nn >> 3) & 1;
    const int w8   = w & 7;               // row-group
    const bool heavy = (w < 8);           // i,g + cell update

    const bool ball = (blk >= NPBLK);
    const float* w_ih = ball ? b_w_ih : p_w_ih;
    const float* w_hh = ball ? b_w_hh : p_w_hh;
    const float* bih  = ball ? b_b_ih : p_b_ih;
    const float* bhh  = ball ? b_b_hh : p_b_hh;
    const float* xg   = ball ? (x_ball    + (size_t)(blk - NPBLK) * NB * TSTEPS * 2)
                             : (x_players + (size_t)blk * NB * TSTEPS * 2);

    __shared__ __align__(16) _Float16 b_sh[2][NB * BSTR];
    __shared__ __align__(16) float x_sh[NB * XSTR];
    __shared__ __align__(16) float exFO[8 * 64 * 4];  // [group][lane] packed f,f,o,o
    __shared__ int   flags[8];                        // per-group step counter
    __shared__ __align__(16) float hbuf[NB * HSTR];
    __shared__ float vout[NB * 40];

    for (int i = tid; i < NB * 256; i += 1024)
        x_sh[(i >> 8) * XSTR + (i & 255)] = xg[i];
    for (int i = tid; i < 2 * NB * BSTR / 2; i += 1024)
        ((int*)b_sh)[i] = 0;
    if (tid < 8) flags[tid] = 0;

    // ---- A fragments: 2 m-tiles/wave. tile t covers gate-rows [16t,16t+16).
    // heavy w: tiles w (gate i rows) and w+16 (gate g rows);
    // light w+8: tiles w+8 (gate f) and w+24 (gate o).
    f16x8 afr[2][KT];
    #pragma unroll
    for (int ti = 0; ti < 2; ++ti) {
        const int r = 16 * (w + 16 * ti) + nn;
        const float* wr = w_hh + (size_t)r * HDIM;
        #pragma unroll
        for (int kt = 0; kt < 4; ++kt) {
            const float* p = wr + kt * 32 + q * 8;
            f16x8 a8;
            #pragma unroll
            for (int j = 0; j < 8; ++j) a8[j] = (_Float16)p[j];
            afr[ti][kt] = a8;
        }
        f16x8 a8 = {};
        if (q == 0) {
            a8[0] = (_Float16)w_ih[2 * r];
            a8[1] = (_Float16)w_ih[2 * r + 1];
            a8[2] = (_Float16)(bih[r] + bhh[r]);
        }
        afr[ti][4] = a8;
    }

    const int cc = nn & 7;                       // owned seq col
    const int r0 = 16 * w8 + 4 * q + 2 * b3;     // first of 2 owned h-rows
    const int exi = (w8 * 64 + lane) * 4;        // lane-aligned exchange slot
    f32x2 c = (f32x2){0.f, 0.f};
    f32x2 h = (f32x2){0.f, 0.f};

    f32x4 zero4 = (f32x4){0.f, 0.f, 0.f, 0.f};
    asm volatile("" : "+v"(zero4));

    __syncthreads();
    if (tid >= 512 && tid < 512 + NB) {   // wave 8 (light): x(0) + '1' aug
        const int j = tid - 512;
        _Float16* br0 = &b_sh[0][j * BSTR];
        br0[128] = (_Float16)x_sh[j * XSTR];
        br0[129] = (_Float16)x_sh[j * XSTR + 1];
        br0[130] = (_Float16)1.0f;
        b_sh[1][j * BSTR + 130] = (_Float16)1.0f;
    }
    __syncthreads();

    f16x8 bfr[KT] = {};   // lanes nn>=8 keep constant-zero B frags

    #pragma unroll 1
    for (int s = 0; s < TSTEPS; ++s) {
        const bool last = (s == TSTEPS - 1);
        const _Float16* bc = &b_sh[s & 1][0];
        _Float16*       bn = &b_sh[(s & 1) ^ 1][0];

        if (nn < 8) {
            #pragma unroll
            for (int kt = 0; kt < KT; ++kt)
                bfr[kt] = *(const f16x8*)(bc + nn * BSTR + kt * 32 + q * 8);
        }

        f32x4 acc[2];
        #pragma unroll
        for (int ti = 0; ti < 2; ++ti)
            acc[ti] = __builtin_amdgcn_mfma_f32_16x16x32_f16(afr[ti][4], bfr[4], zero4, 0, 0, 0);
        #pragma unroll
        for (int kt = 0; kt < 4; ++kt)
            #pragma unroll
            for (int ti = 0; ti < 2; ++ti)
                acc[ti] = __builtin_amdgcn_mfma_f32_16x16x32_f16(afr[ti][kt], bfr[kt], acc[ti], 0, 0, 0);

        // x(s+1) into next buffer (light wave 8 lanes; independent)
        if (!last && tid >= 512 && tid < 512 + NB) {
            const int j = tid - 512;
            const float x0 = x_sh[j * XSTR + 2 * (s + 1)];
            const float x1 = x_sh[j * XSTR + 2 * (s + 1) + 1];
            *(f16x2*)&bn[j * BSTR + 128] = (f16x2){(_Float16)x0, (_Float16)x1};
        }

        // sel8: u[ti] = rows r0, r0+1 of tile ti, col cc
        f32x2 u0, u1;
        u0[0] = dpp_sel8(acc[0][0], acc[0][2]);
        u0[1] = dpp_sel8(acc[0][1], acc[0][3]);
        u1[0] = dpp_sel8(acc[1][0], acc[1][2]);
        u1[1] = dpp_sel8(acc[1][1], acc[1][3]);

        if (!heavy) {
            // light: sigma(f), sigma(o) -> ONE conflict-free ds_write_b128
            const f32x2 ef = exp2v(u0 * -LOG2E);
            const f32x2 eo = exp2v(u1 * -LOG2E);
            const f32x2 ff = rcpv(ef + 1.0f);
            const f32x2 oo = rcpv(eo + 1.0f);
            *(f32x4*)&exFO[exi] = (f32x4){ff[0], ff[1], oo[0], oo[1]};
            __threadfence_block();
            if (lane == 0) ((volatile int*)flags)[w8] = s + 1;
        } else {
            // heavy: i*g via merged rcp, then wait for partner's packed f,o
            const f32x2 ei = exp2v(u0 * -LOG2E);
            const f32x2 eg = exp2v(u1 * (2.0f * LOG2E));
            const f32x2 ig = (eg - 1.0f) * rcpv((ei + 1.0f) * (eg + 1.0f));
            while (((volatile int*)flags)[w8] <= s) { }
            __threadfence_block();
            const f32x4 pk = *(const f32x4*)&exFO[exi];   // ds_read_b128, stride-1
            const f32x2 ff = (f32x2){pk[0], pk[1]};
            const f32x2 oo = (f32x2){pk[2], pk[3]};
            c = __builtin_elementwise_fma(ff, c, ig);
            c = __builtin_elementwise_min(__builtin_elementwise_max(c, (f32x2){-15.f, -15.f}),
                                          (f32x2){15.f, 15.f});
            const f32x2 ec = exp2v(c * (2.0f * LOG2E));
            h = oo * (ec - 1.0f) * rcpv(ec + 1.0f);
            if (!last)
                *(f16x2*)&bn[cc * BSTR + r0] = (f16x2){(_Float16)h[0], (_Float16)h[1]};
        }

        if (!last) __syncthreads();

        // loop-carried AGPR pins: block rematerialization (R1..R5 failure mode)
        asm volatile("" : "+a"(afr[0][0]), "+a"(afr[0][1]), "+a"(afr[0][2]), "+a"(afr[0][3]), "+a"(afr[0][4]));
        asm volatile("" : "+a"(afr[1][0]), "+a"(afr[1][1]), "+a"(afr[1][2]), "+a"(afr[1][3]), "+a"(afr[1][4]));
        asm volatile("" : "+v"(zero4));
    }

    // ---- final h -> LDS (fp32), then fused FC epilogue ----
    if (heavy) {
        hbuf[cc * HSTR + r0]     = h[0];
        hbuf[cc * HSTR + r0 + 1] = h[1];
    }
    __syncthreads();

    if (!ball) {
        for (int o = tid; o < NB * 40; o += 1024) {
            const int j = o / 40, row = o - j * 40;
            const float* wr = fc_w + (size_t)row * 2 * HDIM;        // cols 0..127
            const float* hp = &hbuf[j * HSTR];
            float a0 = fc_b[row], a1 = 0.f, a2 = 0.f, a3 = 0.f;
            #pragma unroll
            for (int k = 0; k < HDIM; k += 4) {
                float4 wv = *(const float4*)(wr + k);
                float4 hv = *(const float4*)(hp + k);
                a0 = __builtin_fmaf(wv.x, hv.x, a0);
                a1 = __builtin_fmaf(wv.y, hv.y, a1);
                a2 = __builtin_fmaf(wv.z, hv.z, a2);
                a3 = __builtin_fmaf(wv.w, hv.w, a3);
            }
            atomicAdd(&out[(size_t)(NB * blk + j) * 40 + row], (a0 + a1) + (a2 + a3));
        }
    } else {
        for (int o = tid; o < NB * 40; o += 1024) {
            const int cb = o / 40, row = o - cb * 40;
            const float* wr = fc_w + (size_t)row * 2 * HDIM + HDIM;  // cols 128..255
            const float* hp = &hbuf[cb * HSTR];
            float a0 = 0.f, a1 = 0.f, a2 = 0.f, a3 = 0.f;
            #pragma unroll
            for (int k = 0; k < HDIM; k += 4) {
                float4 wv = *(const float4*)(wr + k);
                float4 hv = *(const float4*)(hp + k);
                a0 = __builtin_fmaf(wv.x, hv.x, a0);
                a1 = __builtin_fmaf(wv.y, hv.y, a1);
                a2 = __builtin_fmaf(wv.z, hv.z, a2);
                a3 = __builtin_fmaf(wv.w, hv.w, a3);
            }
            vout[cb * 40 + row] = (a0 + a1) + (a2 + a3);
        }
        __syncthreads();
        const int base_batch = (blk - NPBLK) * NB;
        for (int o = tid; o < NB * 22 * 40; o += 1024) {
            const int cb = o / 880, rem = o - cb * 880;
            const int p = rem / 40, row = rem - p * 40;
            atomicAdd(&out[(size_t)((base_batch + cb) * 22 + p) * 40 + row],
                      vout[cb * 40 + row]);
        }
    }
}

extern "C" void kernel_launch(void* const* d_in, const int* in_sizes, int n_in,
                              void* d_out, int out_size, void* d_ws, size_t ws_size,
                              hipStream_t stream) {
    const float* x_players = (const float*)d_in[0];
    const float* x_ball    = (const float*)d_in[1];
    const float* p_w_ih    = (const float*)d_in[2];
    const float* p_w_hh    = (const float*)d_in[3];
    const float* p_b_ih    = (const float*)d_in[4];
    const float* p_b_hh    = (const float*)d_in[5];
    const float* b_w_ih    = (const float*)d_in[6];
    const float* b_w_hh    = (const float*)d_in[7];
    const float* b_b_ih    = (const float*)d_in[8];
    const float* b_b_hh    = (const float*)d_in[9];
    const float* fc_w      = (const float*)d_in[10];
    const float* fc_b      = (const float*)d_in[11];

    hipMemsetAsync(d_out, 0, (size_t)out_size * sizeof(float), stream);

    lstm_fc_kernel<<<dim3(NBLK), dim3(1024), 0, stream>>>(
        x_players, x_ball, p_w_ih, p_w_hh, p_b_ih, p_b_hh,
        b_w_ih, b_w_hh, b_b_ih, b_b_hh, fc_w, fc_b, (float*)d_out);
}